// Round 3
// baseline (20540.091 us; speedup 1.0000x reference)
//
#include <hip/hip_runtime.h>
#include <math.h>

// ---- JAX threefry RNG mode ----
// 0: partitionable (jax >= 0.4.36 default), 32-bit bits = o0 ^ o1  [VERIFIED
//    round 2: absmax 0.0078 = bf16 rounding noise -> bit-exact match]
#define RNG_MODE 0

// B=8, H=8, Dh=64, Dm=512, DF=2048; L = 4096/2048/1024; u = 45/40/35

__host__ __device__ inline void tf2x32(unsigned k0, unsigned k1,
                                       unsigned x0, unsigned x1,
                                       unsigned& o0, unsigned& o1) {
  unsigned ks2 = k0 ^ k1 ^ 0x1BD11BDAu;
#define TF_R(x, r) x0 += x1; x1 = ((x1 << (r)) | (x1 >> (32 - (r)))); x1 ^= x0;
  x0 += k0; x1 += k1;
  TF_R(x1,13) TF_R(x1,15) TF_R(x1,26) TF_R(x1,6)
  x0 += k1; x1 += ks2 + 1u;
  TF_R(x1,17) TF_R(x1,29) TF_R(x1,16) TF_R(x1,24)
  x0 += ks2; x1 += k0 + 2u;
  TF_R(x1,13) TF_R(x1,15) TF_R(x1,26) TF_R(x1,6)
  x0 += k0; x1 += k1 + 3u;
  TF_R(x1,17) TF_R(x1,29) TF_R(x1,16) TF_R(x1,24)
  x0 += k1; x1 += ks2 + 4u;
  TF_R(x1,13) TF_R(x1,15) TF_R(x1,26) TF_R(x1,6)
  x0 += ks2; x1 += k0 + 5u;
#undef TF_R
  o0 = x0; o1 = x1;
}

__global__ void k_idx(int* __restrict__ idx, unsigned k2a, unsigned k2b,
                      int n, int mask, int mode) {
  int j = blockIdx.x * 256 + threadIdx.x;
  if (j >= n) return;
  unsigned o0, o1, bits;
  if (mode == 2) {
    int h = n >> 1;
    if (j < h) { tf2x32(k2a, k2b, (unsigned)j, (unsigned)(j + h), o0, o1); bits = o0; }
    else       { tf2x32(k2a, k2b, (unsigned)(j - h), (unsigned)j, o0, o1); bits = o1; }
  } else {
    tf2x32(k2a, k2b, 0u, (unsigned)j, o0, o1);
    bits = (mode == 0) ? (o0 ^ o1) : o0;
  }
  idx[j] = (int)(bits & (unsigned)mask);
}

// positional-encoding table, fp64 math (matches numpy float64 promotion path)
__global__ void k_pe(float* __restrict__ pe) {
  int t = blockIdx.x * 256 + threadIdx.x;   // over 4096*512
  int l = t >> 9, d = t & 511;
  double div = exp((double)(d & ~1) * (-9.210340371976184 / 512.0));
  double ang = (double)l * div;
  pe[t] = (float)((d & 1) ? cos(ang) : sin(ang));
}

// h = x @ emb_w^T + emb_b + pe   (K=64, 16 rows per block)
__global__ __launch_bounds__(256) void k_embed(const float* __restrict__ x,
    const float* __restrict__ W, const float* __restrict__ eb,
    const float* __restrict__ pe, float* __restrict__ out) {
  __shared__ __align__(16) float xs[16][64];
  int r0 = blockIdx.x * 16;
  int t = threadIdx.x;
  ((float4*)&xs[0][0])[t] = ((const float4*)(x + (size_t)r0 * 64))[t];
  __syncthreads();
  int d0 = t, d1 = t + 256;
  float acc0[16], acc1[16];
#pragma unroll
  for (int r = 0; r < 16; r++) { acc0[r] = 0.f; acc1[r] = 0.f; }
  for (int k = 0; k < 64; k++) {
    float w0 = W[d0 * 64 + k], w1 = W[d1 * 64 + k];
#pragma unroll
    for (int r = 0; r < 16; r++) {
      float xv = xs[r][k];
      acc0[r] = fmaf(xv, w0, acc0[r]);
      acc1[r] = fmaf(xv, w1, acc1[r]);
    }
  }
  float eb0 = eb[d0], eb1 = eb[d1];
#pragma unroll
  for (int r = 0; r < 16; r++) {
    int row = r0 + r;
    int l = row & 4095;
    out[(size_t)row * 512 + d0] = acc0[r] + eb0 + pe[(size_t)l * 512 + d0];
    out[(size_t)row * 512 + d1] = acc1[r] + eb1 + pe[(size_t)l * 512 + d1];
  }
}

// per-(b,h,d) mean over L (fp64)
__global__ __launch_bounds__(256) void k_colmean(const float* __restrict__ X,
    float* __restrict__ meanq, int L) {
  int bh = blockIdx.x, b = bh >> 3, h = bh & 7;
  int w = threadIdx.x >> 6, d = threadIdx.x & 63;
  const float* base = X + (size_t)b * L * 512 + h * 64 + d;
  double s = 0.0;
  for (int l = w; l < L; l += 4) s += (double)base[(size_t)l * 512];
  __shared__ double red[4][64];
  red[w][d] = s;
  __syncthreads();
  if (w == 0)
    meanq[bh * 64 + d] = (float)((red[0][d] + red[1][d] + red[2][d] + red[3][d]) / (double)L);
}

// M[b,h,l] = max_s dot(q_l, q_idx[l,s]) - sum_s(...)/L  (fp64, lane = sample)
__global__ __launch_bounds__(256) void k_M(const float* __restrict__ X,
    const int* __restrict__ idx, float* __restrict__ Mout, int L, int u) {
  int w = threadIdx.x >> 6, lane = threadIdx.x & 63;
  int gl = blockIdx.x * 4 + w;
  int l = gl % L, bh = gl / L, b = bh >> 3, h = bh & 7;
  const float* Xbh = X + (size_t)b * L * 512 + h * 64;
  __shared__ float qs[4][64];
  qs[w][lane] = Xbh[(size_t)l * 512 + lane];
  __syncthreads();
  bool act = lane < u;
  double dot = 0.0;
  if (act) {
    int kidx = idx[l * u + lane];
    const float4* kp = (const float4*)(Xbh + (size_t)kidx * 512);
#pragma unroll
    for (int dq = 0; dq < 16; dq++) {
      float4 kv = kp[dq];
      dot += (double)qs[w][dq * 4 + 0] * (double)kv.x;
      dot += (double)qs[w][dq * 4 + 1] * (double)kv.y;
      dot += (double)qs[w][dq * 4 + 2] * (double)kv.z;
      dot += (double)qs[w][dq * 4 + 3] * (double)kv.w;
    }
  }
  double mv = act ? dot : -1e300;
  double sv = act ? dot : 0.0;
  for (int off = 32; off; off >>= 1) {
    mv = fmax(mv, __shfl_xor(mv, off));
    sv += __shfl_xor(sv, off);
  }
  if (lane == 0) Mout[(size_t)bh * L + l] = (float)(mv - sv / (double)L);
}

// iterative top-u argmax per (b,h); tie -> smaller index (matches lax.top_k)
__global__ __launch_bounds__(256) void k_topk(const float* __restrict__ M,
    int* __restrict__ top, int L, int u) {
  __shared__ float mv[4096];
  __shared__ float rv[256];
  __shared__ int ri[256];
  int bh = blockIdx.x, t = threadIdx.x;
  const float* Mr = M + (size_t)bh * L;
  for (int k = t; k < L; k += 256) mv[k] = Mr[k];
  __syncthreads();
  for (int it = 0; it < u; it++) {
    float bv = -1e30f; int bi = 0x7fffffff;
    for (int k = t; k < L; k += 256) {
      float v = mv[k];
      if (v > bv) { bv = v; bi = k; }
    }
    rv[t] = bv; ri[t] = bi;
    __syncthreads();
    for (int off = 128; off; off >>= 1) {
      if (t < off) {
        float v2 = rv[t + off]; int i2 = ri[t + off];
        if (v2 > rv[t] || (v2 == rv[t] && i2 < ri[t])) { rv[t] = v2; ri[t] = i2; }
      }
      __syncthreads();
    }
    if (t == 0) { top[bh * u + it] = ri[0]; mv[ri[0]] = -1e30f; }
    __syncthreads();
  }
}

// ATT <- broadcast mean
__global__ void k_fill(float* __restrict__ A, const float* __restrict__ meanq, int L) {
  size_t t = (size_t)blockIdx.x * 256 + threadIdx.x;
  size_t e = t * 4;
  int dm = (int)(e & 511);
  int b = (int)((e >> 9) / (size_t)L);
  *(float4*)(A + e) = *(const float4*)(meanq + b * 512 + dm);
}

// S[bh,ur,k] = scale * dot(q_red[ur], q_k) for 64-k tile per block
__global__ __launch_bounds__(256) void k_scores(const float* __restrict__ X,
    const int* __restrict__ top, float* __restrict__ S, int L, int u) {
  __shared__ __align__(16) float ktT[64][68];
  __shared__ __align__(16) float qred[48][64];
  int bh = blockIdx.y, b = bh >> 3, h = bh & 7;
  int k0 = blockIdx.x * 64;
  int t = threadIdx.x;
  const float* Xbh = X + (size_t)b * L * 512 + h * 64;
#pragma unroll
  for (int it = 0; it < 4; it++) {
    int lin = t + it * 256;                // (kk, fi) over 64x16
    int kk = lin >> 4, fi = lin & 15;
    float4 v = *(const float4*)(Xbh + (size_t)(k0 + kk) * 512 + fi * 4);
    ktT[fi * 4 + 0][kk] = v.x; ktT[fi * 4 + 1][kk] = v.y;
    ktT[fi * 4 + 2][kk] = v.z; ktT[fi * 4 + 3][kk] = v.w;
  }
#pragma unroll
  for (int it = 0; it < 3; it++) {
    int lin = t + it * 256;                // (ur, fi) over 48x16
    int ur = lin >> 4, fi = lin & 15;
    if (ur < u) {
      int row = top[bh * u + ur];
      *(float4*)(&qred[ur][fi * 4]) = *(const float4*)(Xbh + (size_t)row * 512 + fi * 4);
    } else if (ur < 48) {
      *(float4*)(&qred[ur][fi * 4]) = make_float4(0.f, 0.f, 0.f, 0.f);
    }
  }
  __syncthreads();
  int xq = t & 15, y = t >> 4;
  float acc[3][4];
#pragma unroll
  for (int j = 0; j < 3; j++)
#pragma unroll
    for (int e = 0; e < 4; e++) acc[j][e] = 0.f;
  for (int d = 0; d < 64; d++) {
    float4 kv = *(const float4*)(&ktT[d][xq * 4]);
#pragma unroll
    for (int j = 0; j < 3; j++) {
      float qv = qred[y * 3 + j][d];
      acc[j][0] = fmaf(qv, kv.x, acc[j][0]);
      acc[j][1] = fmaf(qv, kv.y, acc[j][1]);
      acc[j][2] = fmaf(qv, kv.z, acc[j][2]);
      acc[j][3] = fmaf(qv, kv.w, acc[j][3]);
    }
  }
#pragma unroll
  for (int j = 0; j < 3; j++) {
    int ur = y * 3 + j;
    if (ur < u) {
      float4 o = make_float4(acc[j][0] * 0.125f, acc[j][1] * 0.125f,
                             acc[j][2] * 0.125f, acc[j][3] * 0.125f);
      *(float4*)(S + ((size_t)(bh * u + ur)) * L + k0 + xq * 4) = o;
    }
  }
}

// softmax over k + ctx_top row, written straight into ATT at top position
__global__ __launch_bounds__(256) void k_ctx(const float* __restrict__ X,
    const float* __restrict__ S, const int* __restrict__ top,
    float* __restrict__ A, int L, int u) {
  int ur = blockIdx.x, bh = blockIdx.y, b = bh >> 3, h = bh & 7;
  const float* Srow = S + ((size_t)(bh * u + ur)) * L;
  int t = threadIdx.x;
  __shared__ float wtab[4096];
  __shared__ float rm[256];
  __shared__ double rs[256];
  __shared__ double red[4][64];
  float m = -1e30f;
  for (int k = t; k < L; k += 256) m = fmaxf(m, Srow[k]);
  rm[t] = m; __syncthreads();
  for (int off = 128; off; off >>= 1) {
    if (t < off) rm[t] = fmaxf(rm[t], rm[t + off]);
    __syncthreads();
  }
  float mx = rm[0];
  double s = 0.0;
  for (int k = t; k < L; k += 256) { float e = expf(Srow[k] - mx); wtab[k] = e; s += (double)e; }
  rs[t] = s; __syncthreads();
  for (int off = 128; off; off >>= 1) {
    if (t < off) rs[t] += rs[t + off];
    __syncthreads();
  }
  double inv = 1.0 / rs[0];
  int w = t >> 6, lane = t & 63;
  const float* Xc = X + (size_t)b * L * 512 + h * 64 + lane;
  double acc = 0.0;
  for (int k = w; k < L; k += 4) acc += (double)wtab[k] * (double)Xc[(size_t)k * 512];
  red[w][lane] = acc; __syncthreads();
  if (w == 0) {
    double tot = (red[0][lane] + red[1][lane] + red[2][lane] + red[3][lane]) * inv;
    int row = top[bh * u + ur];
    A[((size_t)b * L + row) * 512 + h * 64 + lane] = (float)tot;
  }
}

// X <- LN(X + A) * gs + gb, in place; one wave per 512-wide row
__global__ __launch_bounds__(256) void k_ln1(float* __restrict__ X,
    const float* __restrict__ A, const float* __restrict__ gs,
    const float* __restrict__ gb) {
  int w = threadIdx.x >> 6, lane = threadIdx.x & 63;
  int row = blockIdx.x * 4 + w;
  float* xr = X + (size_t)row * 512;
  const float* ar = A + (size_t)row * 512;
  float v[8]; double s = 0.0, s2 = 0.0;
#pragma unroll
  for (int i = 0; i < 8; i++) {
    float val = xr[lane + i * 64] + ar[lane + i * 64];
    v[i] = val; s += (double)val; s2 += (double)val * (double)val;
  }
  for (int off = 32; off; off >>= 1) { s += __shfl_xor(s, off); s2 += __shfl_xor(s2, off); }
  double mu = s * (1.0 / 512.0);
  double var = s2 * (1.0 / 512.0) - mu * mu;
  float rsd = (float)(1.0 / sqrt(var + 1e-5));
  float muf = (float)mu;
#pragma unroll
  for (int i = 0; i < 8; i++) {
    int d = lane + i * 64;
    xr[d] = (v[i] - muf) * rsd * gs[d] + gb[d];
  }
}

// out <- LN(X + Y2); optional pair-pool (distil); one wave per output row
__global__ __launch_bounds__(256) void k_ln2(const float* __restrict__ X,
    const float* __restrict__ Y2, const float* __restrict__ gs,
    const float* __restrict__ gb, float* __restrict__ out, int pool) {
  int w = threadIdx.x >> 6, lane = threadIdx.x & 63;
  int orow = blockIdx.x * 4 + w;
  float o[8] = {0.f,0.f,0.f,0.f,0.f,0.f,0.f,0.f};
  int reps = pool ? 2 : 1;
  for (int p = 0; p < reps; p++) {
    int row = pool ? (orow * 2 + p) : orow;
    const float* xr = X + (size_t)row * 512;
    const float* yr = Y2 + (size_t)row * 512;
    float v[8]; double s = 0.0, s2 = 0.0;
#pragma unroll
    for (int i = 0; i < 8; i++) {
      float val = xr[lane + i * 64] + yr[lane + i * 64];
      v[i] = val; s += (double)val; s2 += (double)val * (double)val;
    }
    for (int off = 32; off; off >>= 1) { s += __shfl_xor(s, off); s2 += __shfl_xor(s2, off); }
    double mu = s * (1.0 / 512.0);
    double var = s2 * (1.0 / 512.0) - mu * mu;
    float rsd = (float)(1.0 / sqrt(var + 1e-5));
    float muf = (float)mu;
#pragma unroll
    for (int i = 0; i < 8; i++)
      o[i] += (v[i] - muf) * rsd * gs[lane + i * 64] + gb[lane + i * 64];
  }
  float sc = pool ? 0.5f : 1.0f;
#pragma unroll
  for (int i = 0; i < 8; i++)
    out[(size_t)orow * 512 + lane + i * 64] = o[i] * sc;
}

// C[M,N] = A[M,K] @ B[N,K]^T + bias (+gelu). 128x128 block tile, BK=16,
// 4 waves as 2x2 (each wave 64x64, 8x8 lanes, 8x8 regs/lane).
// LDS reads: 8 distinct stride-8-word addrs/wave -> 2-way banks (free) +
// 8-lane broadcast. Register-double-buffered fragments hide lgkmcnt.
// fp32 vector FMA (no MFMA: output feeds next layer's top_k selection).
template <int GELU>
__global__ __launch_bounds__(256, 2) void k_gemm(const float* __restrict__ A,
    const float* __restrict__ Bm, const float* __restrict__ bias,
    float* __restrict__ C, int N, int K) {
  __shared__ __align__(16) float As[2][16][132];
  __shared__ __align__(16) float Bs[2][16][132];
  const int t = threadIdx.x;
  const int m0 = blockIdx.y * 128, n0 = blockIdx.x * 128;
  const int w = t >> 6, lane = t & 63;
  const int wm = (w >> 1) * 64, wn = (w & 1) * 64;
  const int ty = lane >> 3, tx = lane & 7;
  const int fa = wm + ty * 8;          // A fragment LDS offset (within 128)
  const int fb = wn + tx * 8;          // B fragment LDS offset
  // staging: thread covers A/B rows lr, lr+64, cols lc..lc+3
  const int lr = t >> 2;
  const int lc = (t & 3) * 4;
  const float* Ag = A + (size_t)(m0 + lr) * K + lc;
  const float* Bg = Bm + (size_t)(n0 + lr) * K + lc;
  const size_t rstep = (size_t)64 * K;
  float4 a0, a1, b0, b1;
  a0 = *(const float4*)(Ag); a1 = *(const float4*)(Ag + rstep);
  b0 = *(const float4*)(Bg); b1 = *(const float4*)(Bg + rstep);
#define STORE_TILE(buf)                                                        \
  As[buf][lc+0][lr] = a0.x; As[buf][lc+1][lr] = a0.y;                          \
  As[buf][lc+2][lr] = a0.z; As[buf][lc+3][lr] = a0.w;                          \
  As[buf][lc+0][lr+64] = a1.x; As[buf][lc+1][lr+64] = a1.y;                    \
  As[buf][lc+2][lr+64] = a1.z; As[buf][lc+3][lr+64] = a1.w;                    \
  Bs[buf][lc+0][lr] = b0.x; Bs[buf][lc+1][lr] = b0.y;                          \
  Bs[buf][lc+2][lr] = b0.z; Bs[buf][lc+3][lr] = b0.w;                          \
  Bs[buf][lc+0][lr+64] = b1.x; Bs[buf][lc+1][lr+64] = b1.y;                    \
  Bs[buf][lc+2][lr+64] = b1.z; Bs[buf][lc+3][lr+64] = b1.w;
  STORE_TILE(0)
  __syncthreads();
  float acc[8][8];
#pragma unroll
  for (int i = 0; i < 8; i++)
#pragma unroll
    for (int j = 0; j < 8; j++) acc[i][j] = 0.f;
  const int KT = K >> 4;
  float ar[2][8], br[2][8];
  for (int kt = 0; kt < KT; kt++) {
    const int cur = kt & 1, nxt = cur ^ 1;
    if (kt + 1 < KT) {
      const float* Ap = Ag + (kt + 1) * 16;
      const float* Bp = Bg + (kt + 1) * 16;
      a0 = *(const float4*)(Ap); a1 = *(const float4*)(Ap + rstep);
      b0 = *(const float4*)(Bp); b1 = *(const float4*)(Bp + rstep);
    }
    // prime fragment regs for kk=0
    *(float4*)&ar[0][0] = *(const float4*)&As[cur][0][fa];
    *(float4*)&ar[0][4] = *(const float4*)&As[cur][0][fa + 4];
    *(float4*)&br[0][0] = *(const float4*)&Bs[cur][0][fb];
    *(float4*)&br[0][4] = *(const float4*)&Bs[cur][0][fb + 4];
#pragma unroll
    for (int kk = 0; kk < 16; kk++) {
      const int cb = kk & 1, nb = cb ^ 1;
      if (kk + 1 < 16) {
        *(float4*)&ar[nb][0] = *(const float4*)&As[cur][kk + 1][fa];
        *(float4*)&ar[nb][4] = *(const float4*)&As[cur][kk + 1][fa + 4];
        *(float4*)&br[nb][0] = *(const float4*)&Bs[cur][kk + 1][fb];
        *(float4*)&br[nb][4] = *(const float4*)&Bs[cur][kk + 1][fb + 4];
      }
#pragma unroll
      for (int i = 0; i < 8; i++)
#pragma unroll
        for (int j = 0; j < 8; j++)
          acc[i][j] = fmaf(ar[cb][i], br[cb][j], acc[i][j]);
    }
    if (kt + 1 < KT) {
      __syncthreads();
      STORE_TILE(nxt)
      __syncthreads();
    }
  }
#undef STORE_TILE
#pragma unroll
  for (int i = 0; i < 8; i++) {
    const int gm = m0 + wm + ty * 8 + i;
    float* Cr = C + (size_t)gm * N + n0 + fb;
    float o[8];
#pragma unroll
    for (int j = 0; j < 8; j++) {
      float v = acc[i][j] + bias[n0 + fb + j];
      if (GELU) v = 0.5f * v * (1.0f + erff(v * 0.7071067811865476f));
      o[j] = v;
    }
    *(float4*)Cr = *(float4*)&o[0];
    *(float4*)(Cr + 4) = *(float4*)&o[4];
  }
}

extern "C" void kernel_launch(void* const* d_in, const int* in_sizes, int n_in,
                              void* d_out, int out_size, void* d_ws, size_t ws_size,
                              hipStream_t stream) {
  const float* x     = (const float*)d_in[0];
  const float* emb_w = (const float*)d_in[1];
  const float* emb_b = (const float*)d_in[2];
  const float* ln1_s = (const float*)d_in[3];
  const float* ln1_b = (const float*)d_in[4];
  const float* w1    = (const float*)d_in[5];
  const float* b1    = (const float*)d_in[6];
  const float* w2    = (const float*)d_in[7];
  const float* b2    = (const float*)d_in[8];
  const float* ln2_s = (const float*)d_in[9];
  const float* ln2_b = (const float*)d_in[10];
  const float* out_w = (const float*)d_in[11];
  const float* out_b = (const float*)d_in[12];
  float* outp = (float*)d_out;

  // workspace layout (~211 MiB)
  char* ws = (char*)d_ws;
  if (ws_size < (212ULL << 20)) return;  // insufficient scratch -> fail loudly
  float* PE     = (float*)(ws);                   // 8 MiB
  float* BUF[3] = { (float*)(ws + (8ULL << 20)),
                    (float*)(ws + (72ULL << 20)),
                    (float*)(ws + (136ULL << 20)) };  // 3 x 64 MiB
  float* MB     = (float*)(ws + (200ULL << 20));  // 8 MiB
  int*   IDX    = (int*)  (ws + (208ULL << 20));  // <1 MiB
  int*   TOP    = (int*)  (ws + (209ULL << 20));
  float* MEANQ  = (float*)(ws + (210ULL << 20));

  k_pe<<<4096 * 512 / 256, 256, 0, stream>>>(PE);
  k_embed<<<(8 * 4096) / 16, 256, 0, stream>>>(x, emb_w, emb_b, PE, BUF[0]);

  const int Ls[3] = {4096, 2048, 1024};
  const int us[3] = {45, 40, 35};
  int xi = 0, ai = 1, yi = 2;
  for (int layer = 0; layer < 3; layer++) {
    const int L = Ls[layer], u = us[layer];
    float* X = BUF[xi]; float* A = BUF[ai]; float* Y = BUF[yi];

    // layer key = fold_in(key(42), layer); k2 = second split key
    unsigned Ka, Kb, k2a, k2b;
    tf2x32(0u, 42u, 0u, (unsigned)layer, Ka, Kb);
    tf2x32(Ka, Kb, 0u, 1u, k2a, k2b);
    const int n = L * u;
    k_idx<<<(n + 255) / 256, 256, 0, stream>>>(IDX, k2a, k2b, n, L - 1, RNG_MODE);
    k_colmean<<<64, 256, 0, stream>>>(X, MEANQ, L);
    k_M<<<64 * L / 4, 256, 0, stream>>>(X, IDX, MB, L, u);
    k_topk<<<64, 256, 0, stream>>>(MB, TOP, L, u);
    k_fill<<<8 * L / 2, 256, 0, stream>>>(A, MEANQ, L);
    k_scores<<<dim3(L / 64, 64), 256, 0, stream>>>(X, TOP, Y, L, u);
    k_ctx<<<dim3(u, 64), 256, 0, stream>>>(X, Y, TOP, A, L, u);
    k_ln1<<<8 * L / 4, 256, 0, stream>>>(X, A, ln1_s + layer * 512, ln1_b + layer * 512);

    const int chunks = (8 * L) / 8192;
    for (int c = 0; c < chunks; c++) {
      k_gemm<1><<<dim3(16, 64), 256, 0, stream>>>(
          X + (size_t)c * 8192 * 512, w1 + (size_t)layer * 2048 * 512,
          b1 + layer * 2048, Y, 2048, 512);
      k_gemm<0><<<dim3(4, 64), 256, 0, stream>>>(
          Y, w2 + (size_t)layer * 512 * 2048, b2 + layer * 512,
          A + (size_t)c * 8192 * 512, 512, 2048);
    }
    if (layer < 2)
      k_ln2<<<8 * (L / 2) / 4, 256, 0, stream>>>(X, A, ln2_s + layer * 512,
                                                 ln2_b + layer * 512, Y, 1);
    else
      k_ln2<<<8 * L / 4, 256, 0, stream>>>(X, A, ln2_s + layer * 512,
                                           ln2_b + layer * 512, Y, 0);
    int tswap = xi; xi = yi; yi = ai; ai = tswap;  // next X = Y
  }
  // final projection: (8*1024, 512) @ out_w^T + out_b
  k_gemm<0><<<dim3(4, 64), 256, 0, stream>>>(BUF[xi], out_w, out_b, outp, 512, 512);
}

// Round 4
// 7921.837 us; speedup vs baseline: 2.5928x; 2.5928x over previous
//
#include <hip/hip_runtime.h>
#include <hip/hip_bf16.h>
#include <math.h>

// ---- JAX threefry RNG: partitionable, bits = o0 ^ o1 [VERIFIED round 2] ----

typedef short short8 __attribute__((ext_vector_type(8)));
typedef float f32x4 __attribute__((ext_vector_type(4)));

__host__ __device__ inline void tf2x32(unsigned k0, unsigned k1,
                                       unsigned x0, unsigned x1,
                                       unsigned& o0, unsigned& o1) {
  unsigned ks2 = k0 ^ k1 ^ 0x1BD11BDAu;
#define TF_R(x, r) x0 += x1; x1 = ((x1 << (r)) | (x1 >> (32 - (r)))); x1 ^= x0;
  x0 += k0; x1 += k1;
  TF_R(x1,13) TF_R(x1,15) TF_R(x1,26) TF_R(x1,6)
  x0 += k1; x1 += ks2 + 1u;
  TF_R(x1,17) TF_R(x1,29) TF_R(x1,16) TF_R(x1,24)
  x0 += ks2; x1 += k0 + 2u;
  TF_R(x1,13) TF_R(x1,15) TF_R(x1,26) TF_R(x1,6)
  x0 += k0; x1 += k1 + 3u;
  TF_R(x1,17) TF_R(x1,29) TF_R(x1,16) TF_R(x1,24)
  x0 += k1; x1 += ks2 + 4u;
  TF_R(x1,13) TF_R(x1,15) TF_R(x1,26) TF_R(x1,6)
  x0 += ks2; x1 += k0 + 5u;
#undef TF_R
  o0 = x0; o1 = x1;
}

__global__ void k_idx(int* __restrict__ idx, unsigned k2a, unsigned k2b,
                      int n, int mask) {
  int j = blockIdx.x * 256 + threadIdx.x;
  if (j >= n) return;
  unsigned o0, o1;
  tf2x32(k2a, k2b, 0u, (unsigned)j, o0, o1);
  idx[j] = (int)((o0 ^ o1) & (unsigned)mask);
}

// positional-encoding table, fp64 math (matches numpy float64 promotion path)
__global__ void k_pe(float* __restrict__ pe) {
  int t = blockIdx.x * 256 + threadIdx.x;   // over 4096*512
  int l = t >> 9, d = t & 511;
  double div = exp((double)(d & ~1) * (-9.210340371976184 / 512.0));
  double ang = (double)l * div;
  pe[t] = (float)((d & 1) ? cos(ang) : sin(ang));
}

// h = x @ emb_w^T + emb_b + pe   (K=64, 16 rows per block)
__global__ __launch_bounds__(256) void k_embed(const float* __restrict__ x,
    const float* __restrict__ W, const float* __restrict__ eb,
    const float* __restrict__ pe, float* __restrict__ out) {
  __shared__ __align__(16) float xs[16][64];
  int r0 = blockIdx.x * 16;
  int t = threadIdx.x;
  ((float4*)&xs[0][0])[t] = ((const float4*)(x + (size_t)r0 * 64))[t];
  __syncthreads();
  int d0 = t, d1 = t + 256;
  float acc0[16], acc1[16];
#pragma unroll
  for (int r = 0; r < 16; r++) { acc0[r] = 0.f; acc1[r] = 0.f; }
  for (int k = 0; k < 64; k++) {
    float w0 = W[d0 * 64 + k], w1 = W[d1 * 64 + k];
#pragma unroll
    for (int r = 0; r < 16; r++) {
      float xv = xs[r][k];
      acc0[r] = fmaf(xv, w0, acc0[r]);
      acc1[r] = fmaf(xv, w1, acc1[r]);
    }
  }
  float eb0 = eb[d0], eb1 = eb[d1];
#pragma unroll
  for (int r = 0; r < 16; r++) {
    int row = r0 + r;
    int l = row & 4095;
    out[(size_t)row * 512 + d0] = acc0[r] + eb0 + pe[(size_t)l * 512 + d0];
    out[(size_t)row * 512 + d1] = acc1[r] + eb1 + pe[(size_t)l * 512 + d1];
  }
}

// per-(b,h,d) mean over L (fp64)
__global__ __launch_bounds__(256) void k_colmean(const float* __restrict__ X,
    float* __restrict__ meanq, int L) {
  int bh = blockIdx.x, b = bh >> 3, h = bh & 7;
  int w = threadIdx.x >> 6, d = threadIdx.x & 63;
  const float* base = X + (size_t)b * L * 512 + h * 64 + d;
  double s = 0.0;
  for (int l = w; l < L; l += 4) s += (double)base[(size_t)l * 512];
  __shared__ double red[4][64];
  red[w][d] = s;
  __syncthreads();
  if (w == 0)
    meanq[bh * 64 + d] = (float)((red[0][d] + red[1][d] + red[2][d] + red[3][d]) / (double)L);
}

// M[b,h,l] = max_s dot(q_l, q_idx[l,s]) - sum_s(...)/L  (fp64, lane = sample)
__global__ __launch_bounds__(256) void k_M(const float* __restrict__ X,
    const int* __restrict__ idx, float* __restrict__ Mout, int L, int u) {
  int w = threadIdx.x >> 6, lane = threadIdx.x & 63;
  int gl = blockIdx.x * 4 + w;
  int l = gl % L, bh = gl / L, b = bh >> 3, h = bh & 7;
  const float* Xbh = X + (size_t)b * L * 512 + h * 64;
  __shared__ float qs[4][64];
  qs[w][lane] = Xbh[(size_t)l * 512 + lane];
  __syncthreads();
  bool act = lane < u;
  double dot = 0.0;
  if (act) {
    int kidx = idx[l * u + lane];
    const float4* kp = (const float4*)(Xbh + (size_t)kidx * 512);
#pragma unroll
    for (int dq = 0; dq < 16; dq++) {
      float4 kv = kp[dq];
      dot += (double)qs[w][dq * 4 + 0] * (double)kv.x;
      dot += (double)qs[w][dq * 4 + 1] * (double)kv.y;
      dot += (double)qs[w][dq * 4 + 2] * (double)kv.z;
      dot += (double)qs[w][dq * 4 + 3] * (double)kv.w;
    }
  }
  double mv = act ? dot : -1e300;
  double sv = act ? dot : 0.0;
  for (int off = 32; off; off >>= 1) {
    mv = fmax(mv, __shfl_xor(mv, off));
    sv += __shfl_xor(sv, off);
  }
  if (lane == 0) Mout[(size_t)bh * L + l] = (float)(mv - sv / (double)L);
}

// iterative top-u argmax per (b,h); tie -> smaller index (matches lax.top_k)
__global__ __launch_bounds__(256) void k_topk(const float* __restrict__ M,
    int* __restrict__ top, int L, int u) {
  __shared__ float mv[4096];
  __shared__ float rv[256];
  __shared__ int ri[256];
  int bh = blockIdx.x, t = threadIdx.x;
  const float* Mr = M + (size_t)bh * L;
  for (int k = t; k < L; k += 256) mv[k] = Mr[k];
  __syncthreads();
  for (int it = 0; it < u; it++) {
    float bv = -1e30f; int bi = 0x7fffffff;
    for (int k = t; k < L; k += 256) {
      float v = mv[k];
      if (v > bv) { bv = v; bi = k; }
    }
    rv[t] = bv; ri[t] = bi;
    __syncthreads();
    for (int off = 128; off; off >>= 1) {
      if (t < off) {
        float v2 = rv[t + off]; int i2 = ri[t + off];
        if (v2 > rv[t] || (v2 == rv[t] && i2 < ri[t])) { rv[t] = v2; ri[t] = i2; }
      }
      __syncthreads();
    }
    if (t == 0) { top[bh * u + it] = ri[0]; mv[ri[0]] = -1e30f; }
    __syncthreads();
  }
}

// ATT <- broadcast mean
__global__ void k_fill(float* __restrict__ A, const float* __restrict__ meanq, int L) {
  size_t t = (size_t)blockIdx.x * 256 + threadIdx.x;
  size_t e = t * 4;
  int dm = (int)(e & 511);
  int b = (int)((e >> 9) / (size_t)L);
  *(float4*)(A + e) = *(const float4*)(meanq + b * 512 + dm);
}

// S[bh,ur,k] = scale * dot(q_red[ur], q_k) for 64-k tile per block
__global__ __launch_bounds__(256) void k_scores(const float* __restrict__ X,
    const int* __restrict__ top, float* __restrict__ S, int L, int u) {
  __shared__ __align__(16) float ktT[64][68];
  __shared__ __align__(16) float qred[48][64];
  int bh = blockIdx.y, b = bh >> 3, h = bh & 7;
  int k0 = blockIdx.x * 64;
  int t = threadIdx.x;
  const float* Xbh = X + (size_t)b * L * 512 + h * 64;
#pragma unroll
  for (int it = 0; it < 4; it++) {
    int lin = t + it * 256;                // (kk, fi) over 64x16
    int kk = lin >> 4, fi = lin & 15;
    float4 v = *(const float4*)(Xbh + (size_t)(k0 + kk) * 512 + fi * 4);
    ktT[fi * 4 + 0][kk] = v.x; ktT[fi * 4 + 1][kk] = v.y;
    ktT[fi * 4 + 2][kk] = v.z; ktT[fi * 4 + 3][kk] = v.w;
  }
#pragma unroll
  for (int it = 0; it < 3; it++) {
    int lin = t + it * 256;                // (ur, fi) over 48x16
    int ur = lin >> 4, fi = lin & 15;
    if (ur < u) {
      int row = top[bh * u + ur];
      *(float4*)(&qred[ur][fi * 4]) = *(const float4*)(Xbh + (size_t)row * 512 + fi * 4);
    } else if (ur < 48) {
      *(float4*)(&qred[ur][fi * 4]) = make_float4(0.f, 0.f, 0.f, 0.f);
    }
  }
  __syncthreads();
  int xq = t & 15, y = t >> 4;
  float acc[3][4];
#pragma unroll
  for (int j = 0; j < 3; j++)
#pragma unroll
    for (int e = 0; e < 4; e++) acc[j][e] = 0.f;
  for (int d = 0; d < 64; d++) {
    float4 kv = *(const float4*)(&ktT[d][xq * 4]);
#pragma unroll
    for (int j = 0; j < 3; j++) {
      float qv = qred[y * 3 + j][d];
      acc[j][0] = fmaf(qv, kv.x, acc[j][0]);
      acc[j][1] = fmaf(qv, kv.y, acc[j][1]);
      acc[j][2] = fmaf(qv, kv.z, acc[j][2]);
      acc[j][3] = fmaf(qv, kv.w, acc[j][3]);
    }
  }
#pragma unroll
  for (int j = 0; j < 3; j++) {
    int ur = y * 3 + j;
    if (ur < u) {
      float4 o = make_float4(acc[j][0] * 0.125f, acc[j][1] * 0.125f,
                             acc[j][2] * 0.125f, acc[j][3] * 0.125f);
      *(float4*)(S + ((size_t)(bh * u + ur)) * L + k0 + xq * 4) = o;
    }
  }
}

// softmax over k + ctx_top row, written straight into ATT at top position
__global__ __launch_bounds__(256) void k_ctx(const float* __restrict__ X,
    const float* __restrict__ S, const int* __restrict__ top,
    float* __restrict__ A, int L, int u) {
  int ur = blockIdx.x, bh = blockIdx.y, b = bh >> 3, h = bh & 7;
  const float* Srow = S + ((size_t)(bh * u + ur)) * L;
  int t = threadIdx.x;
  __shared__ float wtab[4096];
  __shared__ float rm[256];
  __shared__ double rs[256];
  __shared__ double red[4][64];
  float m = -1e30f;
  for (int k = t; k < L; k += 256) m = fmaxf(m, Srow[k]);
  rm[t] = m; __syncthreads();
  for (int off = 128; off; off >>= 1) {
    if (t < off) rm[t] = fmaxf(rm[t], rm[t + off]);
    __syncthreads();
  }
  float mx = rm[0];
  double s = 0.0;
  for (int k = t; k < L; k += 256) { float e = expf(Srow[k] - mx); wtab[k] = e; s += (double)e; }
  rs[t] = s; __syncthreads();
  for (int off = 128; off; off >>= 1) {
    if (t < off) rs[t] += rs[t + off];
    __syncthreads();
  }
  double inv = 1.0 / rs[0];
  int w = t >> 6, lane = t & 63;
  const float* Xc = X + (size_t)b * L * 512 + h * 64 + lane;
  double acc = 0.0;
  for (int k = w; k < L; k += 4) acc += (double)wtab[k] * (double)Xc[(size_t)k * 512];
  red[w][lane] = acc; __syncthreads();
  if (w == 0) {
    double tot = (red[0][lane] + red[1][lane] + red[2][lane] + red[3][lane]) * inv;
    int row = top[bh * u + ur];
    A[((size_t)b * L + row) * 512 + h * 64 + lane] = (float)tot;
  }
}

// X <- LN(X + A) * gs + gb, in place; one wave per 512-wide row
__global__ __launch_bounds__(256) void k_ln1(float* __restrict__ X,
    const float* __restrict__ A, const float* __restrict__ gs,
    const float* __restrict__ gb) {
  int w = threadIdx.x >> 6, lane = threadIdx.x & 63;
  int row = blockIdx.x * 4 + w;
  float* xr = X + (size_t)row * 512;
  const float* ar = A + (size_t)row * 512;
  float v[8]; double s = 0.0, s2 = 0.0;
#pragma unroll
  for (int i = 0; i < 8; i++) {
    float val = xr[lane + i * 64] + ar[lane + i * 64];
    v[i] = val; s += (double)val; s2 += (double)val * (double)val;
  }
  for (int off = 32; off; off >>= 1) { s += __shfl_xor(s, off); s2 += __shfl_xor(s2, off); }
  double mu = s * (1.0 / 512.0);
  double var = s2 * (1.0 / 512.0) - mu * mu;
  float rsd = (float)(1.0 / sqrt(var + 1e-5));
  float muf = (float)mu;
#pragma unroll
  for (int i = 0; i < 8; i++) {
    int d = lane + i * 64;
    xr[d] = (v[i] - muf) * rsd * gs[d] + gb[d];
  }
}

// out <- LN(X + Y2); optional pair-pool (distil); one wave per output row
__global__ __launch_bounds__(256) void k_ln2(const float* __restrict__ X,
    const float* __restrict__ Y2, const float* __restrict__ gs,
    const float* __restrict__ gb, float* __restrict__ out, int pool) {
  int w = threadIdx.x >> 6, lane = threadIdx.x & 63;
  int orow = blockIdx.x * 4 + w;
  float o[8] = {0.f,0.f,0.f,0.f,0.f,0.f,0.f,0.f};
  int reps = pool ? 2 : 1;
  for (int p = 0; p < reps; p++) {
    int row = pool ? (orow * 2 + p) : orow;
    const float* xr = X + (size_t)row * 512;
    const float* yr = Y2 + (size_t)row * 512;
    float v[8]; double s = 0.0, s2 = 0.0;
#pragma unroll
    for (int i = 0; i < 8; i++) {
      float val = xr[lane + i * 64] + yr[lane + i * 64];
      v[i] = val; s += (double)val; s2 += (double)val * (double)val;
    }
    for (int off = 32; off; off >>= 1) { s += __shfl_xor(s, off); s2 += __shfl_xor(s2, off); }
    double mu = s * (1.0 / 512.0);
    double var = s2 * (1.0 / 512.0) - mu * mu;
    float rsd = (float)(1.0 / sqrt(var + 1e-5));
    float muf = (float)mu;
#pragma unroll
    for (int i = 0; i < 8; i++)
      o[i] += (v[i] - muf) * rsd * gs[lane + i * 64] + gb[lane + i * 64];
  }
  float sc = pool ? 0.5f : 1.0f;
#pragma unroll
  for (int i = 0; i < 8; i++)
    out[(size_t)orow * 512 + lane + i * 64] = o[i] * sc;
}

// ---------------- bf16x3 MFMA GEMM ----------------
// C[M,N] = A[M,K] @ B[N,K]^T + bias (+gelu), fp32 in/out.
// Each fp32 operand split x = hi + mid + lo (3x RNE bf16 -> ~24-bit mantissa);
// product = hi*hi + hi*mid + mid*hi + mid*mid + hi*lo + lo*hi (6 MFMAs,
// dropped terms ~2^-24 rel) -> fp32-faithful, safe for downstream top_k.
// Tile: 128x128, 4 waves (2x2), wave = 4x4 tiles of mfma_f32_16x16x32_bf16.
// LDS holds split tiles in fragment order [tile][lane][8bf16] so fragment
// loads are linear ds_read_b128 (conflict-free).
// A-frag: lane holds A[m=lane&15][k=(lane>>4)*8+j]; B-frag: B[n=lane&15][k=...]
// (B operand of MFMA is K-major so [N][K] rows load identically to A).
// C/D: col=lane&15, row=(lane>>4)*4+reg [verified layout].

__device__ inline unsigned bsplit(float x, float y, float& rx, float& ry) {
  union { __hip_bfloat162 h; unsigned u; } c;
  c.h = __float22bfloat162_rn(make_float2(x, y));
  rx = x - __uint_as_float(c.u << 16);
  ry = y - __uint_as_float(c.u & 0xffff0000u);
  return c.u;
}

__device__ inline void split3_store(char* hi, float4 v0, float4 v1) {
  uint4 H, M, L; float r[8], r2[8]; float d0, d1;
  H.x = bsplit(v0.x, v0.y, r[0], r[1]);
  H.y = bsplit(v0.z, v0.w, r[2], r[3]);
  H.z = bsplit(v1.x, v1.y, r[4], r[5]);
  H.w = bsplit(v1.z, v1.w, r[6], r[7]);
  M.x = bsplit(r[0], r[1], r2[0], r2[1]);
  M.y = bsplit(r[2], r[3], r2[2], r2[3]);
  M.z = bsplit(r[4], r[5], r2[4], r2[5]);
  M.w = bsplit(r[6], r[7], r2[6], r2[7]);
  L.x = bsplit(r2[0], r2[1], d0, d1);
  L.y = bsplit(r2[2], r2[3], d0, d1);
  L.z = bsplit(r2[4], r2[5], d0, d1);
  L.w = bsplit(r2[6], r2[7], d0, d1);
  *(uint4*)(hi)         = H;
  *(uint4*)(hi + 8192)  = M;   // mid plane
  *(uint4*)(hi + 16384) = L;   // lo plane
}

template <int GELU>
__global__ void k_gemm(const float* __restrict__ A,
    const float* __restrict__ Bm, const float* __restrict__ bias,
    float* __restrict__ C, int N, int K) {
  // LDS: A planes hi/mid/lo @ 0/8192/16384 ; B planes @ +24576
  __shared__ __align__(16) char lds[49152];
  const int t = threadIdx.x;
  const int m0 = blockIdx.y * 128, n0 = blockIdx.x * 128;
  const int lane = t & 63;
  const int quad = lane >> 4;      // 0..3
  const int rit = lane & 15;       // row within 16-tile
  const int qc = quad * 8;         // k offset within 32
  const int tta = t >> 6;          // staging low tile 0..3 (high = +4)
  // staging global pointers (slot low: tile tta, slot high: tile tta+4)
  const float* Ag0 = A + (size_t)(m0 + tta * 16 + rit) * K + qc;
  const float* Ag1 = Ag0 + (size_t)64 * K;
  const float* Bg0 = Bm + (size_t)(n0 + tta * 16 + rit) * K + qc;
  const float* Bg1 = Bg0 + (size_t)64 * K;
  const int ldsS0 = tta * 1024 + lane * 16;      // hi-plane offset, low slot
  const int ldsS1 = ldsS0 + 4096;                // high slot (tile +4)
  // compute-side wave mapping: 2x2 waves, 4x4 tiles each
  const int w = t >> 6;
  const int wm = (w >> 1) * 4, wn = (w & 1) * 4; // tile indices
  f32x4 acc[4][4];
#pragma unroll
  for (int i = 0; i < 4; i++)
#pragma unroll
    for (int j = 0; j < 4; j++) acc[i][j] = (f32x4){0.f, 0.f, 0.f, 0.f};
  // prefetch kt=0
  float4 pa0a = *(const float4*)(Ag0), pa0b = *(const float4*)(Ag0 + 4);
  float4 pa1a = *(const float4*)(Ag1), pa1b = *(const float4*)(Ag1 + 4);
  float4 pb0a = *(const float4*)(Bg0), pb0b = *(const float4*)(Bg0 + 4);
  float4 pb1a = *(const float4*)(Bg1), pb1b = *(const float4*)(Bg1 + 4);
  const int KT = K >> 5;
  for (int kt = 0; kt < KT; kt++) {
    __syncthreads();   // prior iteration's fragment reads complete
    split3_store(lds + ldsS0, pa0a, pa0b);
    split3_store(lds + ldsS1, pa1a, pa1b);
    split3_store(lds + 24576 + ldsS0, pb0a, pb0b);
    split3_store(lds + 24576 + ldsS1, pb1a, pb1b);
    __syncthreads();
    if (kt + 1 < KT) {
      const int ko = (kt + 1) * 32;
      pa0a = *(const float4*)(Ag0 + ko); pa0b = *(const float4*)(Ag0 + ko + 4);
      pa1a = *(const float4*)(Ag1 + ko); pa1b = *(const float4*)(Ag1 + ko + 4);
      pb0a = *(const float4*)(Bg0 + ko); pb0b = *(const float4*)(Bg0 + ko + 4);
      pb1a = *(const float4*)(Bg1 + ko); pb1b = *(const float4*)(Bg1 + ko + 4);
    }
    // load all A fragments for this wave's 4 m-tiles (3 planes)
    short8 af[3][4];
#pragma unroll
    for (int p = 0; p < 3; p++)
#pragma unroll
      for (int mi = 0; mi < 4; mi++)
        af[p][mi] = *(const short8*)(lds + p * 8192 + (wm + mi) * 1024 + lane * 16);
#pragma unroll
    for (int ni = 0; ni < 4; ni++) {
      const char* bb = lds + 24576 + (wn + ni) * 1024 + lane * 16;
      short8 bh = *(const short8*)(bb);
      short8 bm = *(const short8*)(bb + 8192);
      short8 bl = *(const short8*)(bb + 16384);
#pragma unroll
      for (int mi = 0; mi < 4; mi++) {
        f32x4 c = acc[mi][ni];
        c = __builtin_amdgcn_mfma_f32_16x16x32_bf16(af[0][mi], bh, c, 0, 0, 0);
        c = __builtin_amdgcn_mfma_f32_16x16x32_bf16(af[0][mi], bm, c, 0, 0, 0);
        c = __builtin_amdgcn_mfma_f32_16x16x32_bf16(af[1][mi], bh, c, 0, 0, 0);
        c = __builtin_amdgcn_mfma_f32_16x16x32_bf16(af[1][mi], bm, c, 0, 0, 0);
        c = __builtin_amdgcn_mfma_f32_16x16x32_bf16(af[0][mi], bl, c, 0, 0, 0);
        c = __builtin_amdgcn_mfma_f32_16x16x32_bf16(af[2][mi], bh, c, 0, 0, 0);
        acc[mi][ni] = c;
      }
    }
  }
  // epilogue: C/D layout col=lane&15, row=quad*4+e
#pragma unroll
  for (int mi = 0; mi < 4; mi++) {
    const int gr0 = m0 + (wm + mi) * 16 + quad * 4;
#pragma unroll
    for (int ni = 0; ni < 4; ni++) {
      const int gc = n0 + (wn + ni) * 16 + rit;
      const float bia = bias[gc];
#pragma unroll
      for (int e = 0; e < 4; e++) {
        float v = acc[mi][ni][e] + bia;
        if (GELU) v = 0.5f * v * (1.0f + erff(v * 0.7071067811865476f));
        C[(size_t)(gr0 + e) * N + gc] = v;
      }
    }
  }
}

extern "C" void kernel_launch(void* const* d_in, const int* in_sizes, int n_in,
                              void* d_out, int out_size, void* d_ws, size_t ws_size,
                              hipStream_t stream) {
  const float* x     = (const float*)d_in[0];
  const float* emb_w = (const float*)d_in[1];
  const float* emb_b = (const float*)d_in[2];
  const float* ln1_s = (const float*)d_in[3];
  const float* ln1_b = (const float*)d_in[4];
  const float* w1    = (const float*)d_in[5];
  const float* b1    = (const float*)d_in[6];
  const float* w2    = (const float*)d_in[7];
  const float* b2    = (const float*)d_in[8];
  const float* ln2_s = (const float*)d_in[9];
  const float* ln2_b = (const float*)d_in[10];
  const float* out_w = (const float*)d_in[11];
  const float* out_b = (const float*)d_in[12];
  float* outp = (float*)d_out;

  // workspace layout (~211 MiB)
  char* ws = (char*)d_ws;
  if (ws_size < (212ULL << 20)) return;  // insufficient scratch -> fail loudly
  float* PE     = (float*)(ws);                   // 8 MiB
  float* BUF[3] = { (float*)(ws + (8ULL << 20)),
                    (float*)(ws + (72ULL << 20)),
                    (float*)(ws + (136ULL << 20)) };  // 3 x 64 MiB
  float* MB     = (float*)(ws + (200ULL << 20));  // 8 MiB
  int*   IDX    = (int*)  (ws + (208ULL << 20));  // <1 MiB
  int*   TOP    = (int*)  (ws + (209ULL << 20));
  float* MEANQ  = (float*)(ws + (210ULL << 20));

  k_pe<<<4096 * 512 / 256, 256, 0, stream>>>(PE);
  k_embed<<<(8 * 4096) / 16, 256, 0, stream>>>(x, emb_w, emb_b, PE, BUF[0]);

  const int Ls[3] = {4096, 2048, 1024};
  const int us[3] = {45, 40, 35};
  int xi = 0, ai = 1, yi = 2;
  for (int layer = 0; layer < 3; layer++) {
    const int L = Ls[layer], u = us[layer];
    float* X = BUF[xi]; float* A = BUF[ai]; float* Y = BUF[yi];

    // layer key = fold_in(key(42), layer); k2 = second split key
    unsigned Ka, Kb, k2a, k2b;
    tf2x32(0u, 42u, 0u, (unsigned)layer, Ka, Kb);
    tf2x32(Ka, Kb, 0u, 1u, k2a, k2b);
    const int n = L * u;
    k_idx<<<(n + 255) / 256, 256, 0, stream>>>(IDX, k2a, k2b, n, L - 1);
    k_colmean<<<64, 256, 0, stream>>>(X, MEANQ, L);
    k_M<<<64 * L / 4, 256, 0, stream>>>(X, IDX, MB, L, u);
    k_topk<<<64, 256, 0, stream>>>(MB, TOP, L, u);
    k_fill<<<8 * L / 2, 256, 0, stream>>>(A, MEANQ, L);
    k_scores<<<dim3(L / 64, 64), 256, 0, stream>>>(X, TOP, Y, L, u);
    k_ctx<<<dim3(u, 64), 256, 0, stream>>>(X, Y, TOP, A, L, u);
    k_ln1<<<8 * L / 4, 256, 0, stream>>>(X, A, ln1_s + layer * 512, ln1_b + layer * 512);

    const int chunks = (8 * L) / 8192;
    for (int c = 0; c < chunks; c++) {
      k_gemm<1><<<dim3(16, 64), 256, 0, stream>>>(
          X + (size_t)c * 8192 * 512, w1 + (size_t)layer * 2048 * 512,
          b1 + layer * 2048, Y, 2048, 512);
      k_gemm<0><<<dim3(4, 64), 256, 0, stream>>>(
          Y, w2 + (size_t)layer * 512 * 2048, b2 + layer * 512,
          A + (size_t)c * 8192 * 512, 512, 2048);
    }
    if (layer < 2)
      k_ln2<<<8 * (L / 2) / 4, 256, 0, stream>>>(X, A, ln2_s + layer * 512,
                                                 ln2_b + layer * 512, Y, 1);
    else
      k_ln2<<<8 * L / 4, 256, 0, stream>>>(X, A, ln2_s + layer * 512,
                                           ln2_b + layer * 512, Y, 0);
    int tswap = xi; xi = yi; yi = ai; ai = tswap;  // next X = Y
  }
  // final projection: (8*1024, 512) @ out_w^T + out_b
  k_gemm<0><<<dim3(4, 64), 256, 0, stream>>>(BUF[xi], out_w, out_b, outp, 512, 512);
}